// Round 1
// baseline (536.541 us; speedup 1.0000x reference)
//
#include <hip/hip_runtime.h>

#define D_MODEL 1024
#define NUM_HEADS 16
#define DH 64
#define B_SZ 2
#define T_SZ 2048
#define M_ROWS (B_SZ * T_SZ)   // 4096

typedef __bf16 bf16;
typedef __bf16 bf16x4 __attribute__((ext_vector_type(4)));
typedef __bf16 bf16x8 __attribute__((ext_vector_type(8)));
typedef float f32x4 __attribute__((ext_vector_type(4)));

// ---------------------------------------------------------------------------
// 1. Cast fp32 -> bf16: X (4096x1024) + Wq/Wk/Wv/Wo (1024x1024 each)
// ---------------------------------------------------------------------------
#define NX (M_ROWS * D_MODEL / 4)     // 1,048,576 float4 groups
#define NW (D_MODEL * D_MODEL / 4)    //   262,144 float4 groups (2^18)

__global__ __launch_bounds__(256) void cast_all(
    const float* __restrict__ X, const float* __restrict__ Wq,
    const float* __restrict__ Wk, const float* __restrict__ Wv,
    const float* __restrict__ Wo,
    bf16* __restrict__ Xb, bf16* __restrict__ Wqb, bf16* __restrict__ Wkb,
    bf16* __restrict__ Wvb, bf16* __restrict__ Wob) {
  int i = blockIdx.x * 256 + threadIdx.x;   // grid sized exactly NX + 4*NW
  const float* s; bf16* d; int off;
  if (i < NX) {
    s = X; d = Xb; off = i;
  } else {
    int j = i - NX;
    int w = j >> 18;            // NW == 2^18
    off = j & (NW - 1);
    if (w == 0)      { s = Wq; d = Wqb; }
    else if (w == 1) { s = Wk; d = Wkb; }
    else if (w == 2) { s = Wv; d = Wvb; }
    else             { s = Wo; d = Wob; }
  }
  float4 v = ((const float4*)s)[off];
  bf16x4 o;
  o[0] = (bf16)v.x; o[1] = (bf16)v.y; o[2] = (bf16)v.z; o[3] = (bf16)v.w;
  ((bf16x4*)d)[off] = o;
}

// ---------------------------------------------------------------------------
// 2. QKV GEMM: [Q|K|V](m, n) = sum_k X(m,k) * W{q,k,v}(n,k)   (NT layout)
//    64x64 tile per block; 4 waves, each 16 rows x 64 cols.
// ---------------------------------------------------------------------------
__global__ __launch_bounds__(256) void qkv_gemm(
    const bf16* __restrict__ Xb,
    const bf16* __restrict__ Wqb, const bf16* __restrict__ Wkb,
    const bf16* __restrict__ Wvb,
    bf16* __restrict__ Q, bf16* __restrict__ K, bf16* __restrict__ V) {
  int tile_m = blockIdx.x;            // 64 tiles over M=4096
  int tile_n = blockIdx.y;            // 48 tiles over N=3072
  int wave = threadIdx.x >> 6;
  int lane = threadIdx.x & 63;
  int l15 = lane & 15, quad = lane >> 4;

  int gn = tile_n * 64;               // global col in [0,3072)
  int sel = gn >> 10;                 // 0=Q,1=K,2=V (64 | 1024, no straddle)
  int nb = gn & 1023;                 // col base within the 1024-wide output
  const bf16* W; bf16* Out;
  if (sel == 0)      { W = Wqb; Out = Q; }
  else if (sel == 1) { W = Wkb; Out = K; }
  else               { W = Wvb; Out = V; }

  int row0 = tile_m * 64 + wave * 16;
  const bf16* Arow = Xb + (size_t)(row0 + l15) * D_MODEL + quad * 8;
  const bf16* Brow[4];
#pragma unroll
  for (int c = 0; c < 4; ++c)
    Brow[c] = W + (size_t)(nb + c * 16 + l15) * D_MODEL + quad * 8;

  f32x4 acc[4];
#pragma unroll
  for (int c = 0; c < 4; ++c) acc[c] = (f32x4){0.f, 0.f, 0.f, 0.f};

  for (int k = 0; k < D_MODEL; k += 32) {
    bf16x8 a = *(const bf16x8*)(Arow + k);
#pragma unroll
    for (int c = 0; c < 4; ++c) {
      bf16x8 bfr = *(const bf16x8*)(Brow[c] + k);
      acc[c] = __builtin_amdgcn_mfma_f32_16x16x32_bf16(a, bfr, acc[c], 0, 0, 0);
    }
  }

  // C layout: col = lane&15, row = quad*4 + reg   [measured m89]
  int orow0 = row0 + quad * 4;
#pragma unroll
  for (int c = 0; c < 4; ++c) {
    int col = nb + c * 16 + l15;
#pragma unroll
    for (int r = 0; r < 4; ++r)
      Out[(size_t)(orow0 + r) * D_MODEL + col] = (bf16)acc[c][r];
  }
}

// ---------------------------------------------------------------------------
// 3. RoPE in place on Q and K (interleaved pairs within each head's 64 dims)
// ---------------------------------------------------------------------------
__global__ __launch_bounds__(256) void rope_kernel(
    bf16* __restrict__ Q, bf16* __restrict__ K, const int* __restrict__ pos) {
  int idx = blockIdx.x * 256 + threadIdx.x;  // 4096*16*32 = 2,097,152 threads
  int i = idx & 31;                          // pair index within head
  int h = (idx >> 5) & 15;
  int row = idx >> 9;                        // 0..4095
  int t = row & (T_SZ - 1);
  float p = (float)pos[t];
  // inv_freq = 10000^(-2i/64) = exp(-i * ln(10000)/32)
  float freq = expf(-(float)i * 0.28782313662425f);
  float ang = p * freq;
  float s, c;
  sincosf(ang, &s, &c);
  size_t base = (size_t)row * D_MODEL + h * DH + 2 * i;
  float q1 = (float)Q[base], q2 = (float)Q[base + 1];
  Q[base]     = (bf16)(q1 * c - q2 * s);
  Q[base + 1] = (bf16)(q1 * s + q2 * c);
  float k1 = (float)K[base], k2 = (float)K[base + 1];
  K[base]     = (bf16)(k1 * c - k2 * s);
  K[base + 1] = (bf16)(k1 * s + k2 * c);
}

// ---------------------------------------------------------------------------
// 4. Causal flash attention. Block = (b,h, q-tile of 64). 4 waves x 16 rows.
//    kv-tiles of 32. Online softmax fp32; P->A-operand via per-wave LDS.
// ---------------------------------------------------------------------------
__global__ __launch_bounds__(256) void attn_kernel(
    const bf16* __restrict__ Q, const bf16* __restrict__ K,
    const bf16* __restrict__ V, bf16* __restrict__ AO) {
  __shared__ bf16 Pbuf[4][16 * 32];

  int bh = blockIdx.x;       // 0..31
  int qt = blockIdx.y;       // 0..31
  int bb = bh >> 4, h = bh & 15;
  int wave = threadIdx.x >> 6, lane = threadIdx.x & 63;
  int l15 = lane & 15, quad = lane >> 4;

  int q_local = qt * 64 + wave * 16;            // q row base within T
  size_t grow0 = (size_t)bb * T_SZ + q_local;   // global row base

  const bf16* Qbase = Q + (grow0 + l15) * D_MODEL + h * DH + quad * 8;
  bf16x8 aq0 = *(const bf16x8*)(Qbase);
  bf16x8 aq1 = *(const bf16x8*)(Qbase + 32);

  f32x4 o[4];
#pragma unroll
  for (int nt = 0; nt < 4; ++nt) o[nt] = (f32x4){0.f, 0.f, 0.f, 0.f};
  float m_i[4], l_i[4];
#pragma unroll
  for (int r = 0; r < 4; ++r) { m_i[r] = -1e30f; l_i[r] = 0.f; }

  bf16* Pw = Pbuf[wave];
  int ntiles = qt * 2 + 2;                      // uniform across the block

  for (int t = 0; t < ntiles; ++t) {
    int kv0 = t * 32;

    // ---- S = scale * Q K^T  (16 q-rows x 32 kv-cols) ----
    const bf16* Kb0 = K + ((size_t)bb * T_SZ + kv0 + l15) * D_MODEL + h * DH + quad * 8;
    const bf16* Kb1 = Kb0 + (size_t)16 * D_MODEL;
    f32x4 s0 = (f32x4){0.f, 0.f, 0.f, 0.f};
    f32x4 s1 = (f32x4){0.f, 0.f, 0.f, 0.f};
    {
      bf16x8 b00 = *(const bf16x8*)(Kb0);
      bf16x8 b01 = *(const bf16x8*)(Kb0 + 32);
      s0 = __builtin_amdgcn_mfma_f32_16x16x32_bf16(aq0, b00, s0, 0, 0, 0);
      s0 = __builtin_amdgcn_mfma_f32_16x16x32_bf16(aq1, b01, s0, 0, 0, 0);
      bf16x8 b10 = *(const bf16x8*)(Kb1);
      bf16x8 b11 = *(const bf16x8*)(Kb1 + 32);
      s1 = __builtin_amdgcn_mfma_f32_16x16x32_bf16(aq0, b10, s1, 0, 0, 0);
      s1 = __builtin_amdgcn_mfma_f32_16x16x32_bf16(aq1, b11, s1, 0, 0, 0);
    }

    // ---- scale + causal mask ----
    float vals[2][4];
#pragma unroll
    for (int ct = 0; ct < 2; ++ct) {
      int kc = kv0 + ct * 16 + l15;
#pragma unroll
      for (int r = 0; r < 4; ++r) {
        int qr = q_local + quad * 4 + r;
        float v = (ct == 0 ? s0[r] : s1[r]) * 0.125f;  // 1/sqrt(64)
        vals[ct][r] = (kc > qr) ? -1e30f : v;
      }
    }

    // ---- row max across the 16-lane col group ----
    float mloc[4];
#pragma unroll
    for (int r = 0; r < 4; ++r) mloc[r] = fmaxf(vals[0][r], vals[1][r]);
#pragma unroll
    for (int off = 1; off < 16; off <<= 1) {
#pragma unroll
      for (int r = 0; r < 4; ++r)
        mloc[r] = fmaxf(mloc[r], __shfl_xor(mloc[r], off));
    }

    float alpha[4];
#pragma unroll
    for (int r = 0; r < 4; ++r) {
      float mn = fmaxf(m_i[r], mloc[r]);
      alpha[r] = __expf(m_i[r] - mn);
      m_i[r] = mn;
    }

    // ---- P = exp(S - m), row-sum ----
    float psum[4] = {0.f, 0.f, 0.f, 0.f};
#pragma unroll
    for (int ct = 0; ct < 2; ++ct)
#pragma unroll
      for (int r = 0; r < 4; ++r) {
        float p = __expf(vals[ct][r] - m_i[r]);
        vals[ct][r] = p;
        psum[r] += p;
      }
#pragma unroll
    for (int off = 1; off < 16; off <<= 1) {
#pragma unroll
      for (int r = 0; r < 4; ++r) psum[r] += __shfl_xor(psum[r], off);
    }
#pragma unroll
    for (int r = 0; r < 4; ++r) l_i[r] = l_i[r] * alpha[r] + psum[r];

    // ---- rescale O accumulator ----
#pragma unroll
    for (int nt = 0; nt < 4; ++nt)
#pragma unroll
      for (int r = 0; r < 4; ++r) o[nt][r] *= alpha[r];

    // ---- P (C-layout) -> LDS -> A-operand layout ----
#pragma unroll
    for (int ct = 0; ct < 2; ++ct)
#pragma unroll
      for (int r = 0; r < 4; ++r)
        Pw[(quad * 4 + r) * 32 + ct * 16 + l15] = (bf16)vals[ct][r];
    __syncthreads();
    bf16x8 ap = *(const bf16x8*)(Pw + l15 * 32 + quad * 8);

    // ---- O += P V ----
    const bf16* Vb = V + ((size_t)bb * T_SZ + kv0 + quad * 8) * D_MODEL + h * DH;
#pragma unroll
    for (int nt = 0; nt < 4; ++nt) {
      bf16x8 bv;
#pragma unroll
      for (int j = 0; j < 8; ++j)
        bv[j] = Vb[(size_t)j * D_MODEL + nt * 16 + l15];
      o[nt] = __builtin_amdgcn_mfma_f32_16x16x32_bf16(ap, bv, o[nt], 0, 0, 0);
    }
    __syncthreads();
  }

  // ---- epilogue: O / l, write bf16 (row-major (B*T, 1024), col = h*64+d) ----
  float inv[4];
#pragma unroll
  for (int r = 0; r < 4; ++r) inv[r] = 1.0f / l_i[r];
#pragma unroll
  for (int nt = 0; nt < 4; ++nt)
#pragma unroll
    for (int r = 0; r < 4; ++r)
      AO[(grow0 + quad * 4 + r) * D_MODEL + h * DH + nt * 16 + l15] =
          (bf16)(o[nt][r] * inv[r]);
}

// ---------------------------------------------------------------------------
// 5. Output GEMM: out(m,n) = sum_k AO(m,k) * Wo(n,k), fp32 output
// ---------------------------------------------------------------------------
__global__ __launch_bounds__(256) void out_gemm(
    const bf16* __restrict__ AO, const bf16* __restrict__ Wob,
    float* __restrict__ out) {
  int tile_m = blockIdx.x;            // 64
  int tile_n = blockIdx.y;            // 16
  int wave = threadIdx.x >> 6;
  int lane = threadIdx.x & 63;
  int l15 = lane & 15, quad = lane >> 4;

  int row0 = tile_m * 64 + wave * 16;
  int nb = tile_n * 64;
  const bf16* Arow = AO + (size_t)(row0 + l15) * D_MODEL + quad * 8;
  const bf16* Brow[4];
#pragma unroll
  for (int c = 0; c < 4; ++c)
    Brow[c] = Wob + (size_t)(nb + c * 16 + l15) * D_MODEL + quad * 8;

  f32x4 acc[4];
#pragma unroll
  for (int c = 0; c < 4; ++c) acc[c] = (f32x4){0.f, 0.f, 0.f, 0.f};

  for (int k = 0; k < D_MODEL; k += 32) {
    bf16x8 a = *(const bf16x8*)(Arow + k);
#pragma unroll
    for (int c = 0; c < 4; ++c) {
      bf16x8 bfr = *(const bf16x8*)(Brow[c] + k);
      acc[c] = __builtin_amdgcn_mfma_f32_16x16x32_bf16(a, bfr, acc[c], 0, 0, 0);
    }
  }

  int orow0 = row0 + quad * 4;
#pragma unroll
  for (int c = 0; c < 4; ++c) {
    int col = nb + c * 16 + l15;
#pragma unroll
    for (int r = 0; r < 4; ++r)
      out[(size_t)(orow0 + r) * D_MODEL + col] = acc[c][r];
  }
}

// ---------------------------------------------------------------------------
extern "C" void kernel_launch(void* const* d_in, const int* in_sizes, int n_in,
                              void* d_out, int out_size, void* d_ws, size_t ws_size,
                              hipStream_t stream) {
  const float* X  = (const float*)d_in[0];
  const float* Wq = (const float*)d_in[1];
  const float* Wk = (const float*)d_in[2];
  const float* Wv = (const float*)d_in[3];
  const float* Wo = (const float*)d_in[4];
  const int*  pos = (const int*)d_in[5];
  float* out = (float*)d_out;

  // workspace layout (bf16 buffers, all 16B aligned)
  char* w = (char*)d_ws;
  bf16* Xb  = (bf16*)w;                 w += (size_t)M_ROWS * D_MODEL * 2;   // 8 MB
  bf16* Wqb = (bf16*)w;                 w += (size_t)D_MODEL * D_MODEL * 2;  // 2 MB
  bf16* Wkb = (bf16*)w;                 w += (size_t)D_MODEL * D_MODEL * 2;
  bf16* Wvb = (bf16*)w;                 w += (size_t)D_MODEL * D_MODEL * 2;
  bf16* Wob = (bf16*)w;                 w += (size_t)D_MODEL * D_MODEL * 2;
  bf16* Qb  = (bf16*)w;                 w += (size_t)M_ROWS * D_MODEL * 2;
  bf16* Kb  = (bf16*)w;                 w += (size_t)M_ROWS * D_MODEL * 2;
  bf16* Vb  = (bf16*)w;                 w += (size_t)M_ROWS * D_MODEL * 2;
  bf16* AO  = (bf16*)w;                 w += (size_t)M_ROWS * D_MODEL * 2;

  // 1. cast everything to bf16
  cast_all<<<(NX + 4 * NW) / 256, 256, 0, stream>>>(X, Wq, Wk, Wv, Wo,
                                                    Xb, Wqb, Wkb, Wvb, Wob);
  // 2. QKV projection
  qkv_gemm<<<dim3(M_ROWS / 64, 3 * D_MODEL / 64), 256, 0, stream>>>(
      Xb, Wqb, Wkb, Wvb, Qb, Kb, Vb);
  // 3. RoPE on Q, K
  rope_kernel<<<(M_ROWS * NUM_HEADS * 32) / 256, 256, 0, stream>>>(Qb, Kb, pos);
  // 4. causal flash attention
  attn_kernel<<<dim3(B_SZ * NUM_HEADS, T_SZ / 64), 256, 0, stream>>>(Qb, Kb, Vb, AO);
  // 5. output projection
  out_gemm<<<dim3(M_ROWS / 64, D_MODEL / 64), 256, 0, stream>>>(AO, Wob, out);
}

// Round 2
// 313.282 us; speedup vs baseline: 1.7126x; 1.7126x over previous
//
#include <hip/hip_runtime.h>

#define D_MODEL 1024
#define NUM_HEADS 16
#define DH 64
#define B_SZ 2
#define T_SZ 2048
#define M_ROWS (B_SZ * T_SZ)   // 4096

typedef __bf16 bf16;
typedef __bf16 bf16x4 __attribute__((ext_vector_type(4)));
typedef __bf16 bf16x8 __attribute__((ext_vector_type(8)));
typedef float f32x4 __attribute__((ext_vector_type(4)));

// async global->LDS, 16 B per lane. LDS dest is wave-uniform base + lane*16;
// our layouts are arranged so the per-thread pointer equals exactly that.
__device__ __forceinline__ void async_copy16(const bf16* g, bf16* l) {
  __builtin_amdgcn_global_load_lds(
      (const __attribute__((address_space(1))) void*)g,
      (__attribute__((address_space(3))) void*)l, 16, 0, 0);
}

// ---------------------------------------------------------------------------
// 1. Cast fp32 -> bf16: X (4096x1024) + Wq/Wk/Wv/Wo (1024x1024 each)
// ---------------------------------------------------------------------------
#define NX (M_ROWS * D_MODEL / 4)     // 1,048,576 float4 groups
#define NW (D_MODEL * D_MODEL / 4)    //   262,144 float4 groups (2^18)

__global__ __launch_bounds__(256) void cast_all(
    const float* __restrict__ X, const float* __restrict__ Wq,
    const float* __restrict__ Wk, const float* __restrict__ Wv,
    const float* __restrict__ Wo,
    bf16* __restrict__ Xb, bf16* __restrict__ Wqb, bf16* __restrict__ Wkb,
    bf16* __restrict__ Wvb, bf16* __restrict__ Wob) {
  int i = blockIdx.x * 256 + threadIdx.x;
  const float* s; bf16* d; int off;
  if (i < NX) {
    s = X; d = Xb; off = i;
  } else {
    int j = i - NX;
    int w = j >> 18;            // NW == 2^18
    off = j & (NW - 1);
    if (w == 0)      { s = Wq; d = Wqb; }
    else if (w == 1) { s = Wk; d = Wkb; }
    else if (w == 2) { s = Wv; d = Wvb; }
    else             { s = Wo; d = Wob; }
  }
  float4 v = ((const float4*)s)[off];
  bf16x4 o;
  o[0] = (bf16)v.x; o[1] = (bf16)v.y; o[2] = (bf16)v.z; o[3] = (bf16)v.w;
  ((bf16x4*)d)[off] = o;
}

// ---------------------------------------------------------------------------
// 2. QKV GEMM, m97 structure: 128x128 tile, BK=32, global_load_lds staging.
//    [Q|K|V](m,n) = sum_k X(m,k) * W{q,k,v}(n,k)   (NT layout)
// ---------------------------------------------------------------------------
__global__ __launch_bounds__(256) void qkv_gemm(
    const bf16* __restrict__ Xb,
    const bf16* __restrict__ Wqb, const bf16* __restrict__ Wkb,
    const bf16* __restrict__ Wvb,
    bf16* __restrict__ Q, bf16* __restrict__ K, bf16* __restrict__ V) {
  __shared__ bf16 As[128 * 32];
  __shared__ bf16 Bs[128 * 32];

  int tid = threadIdx.x;
  int wave = tid >> 6, lane = tid & 63;
  int wm = wave >> 1, wn = wave & 1;          // 2x2 wave grid, 64x64 each
  int l15 = lane & 15, quad = lane >> 4;

  int row0 = blockIdx.x * 128;
  int col0 = blockIdx.y * 128;                // 0..3071
  int sel = col0 >> 10;                       // 0=Q,1=K,2=V (no straddle)
  int nb = col0 & 1023;
  const bf16* W; bf16* Out;
  if (sel == 0)      { W = Wqb; Out = Q; }
  else if (sel == 1) { W = Wkb; Out = K; }
  else               { W = Wvb; Out = V; }

  // staging: 256 threads x 16B = 64 rows/call (4 chunks per 32-elem row)
  int srow = tid >> 2;       // 0..63
  int schunk = tid & 3;      // *8 elems
  const bf16* Ag = Xb + (size_t)(row0 + srow) * D_MODEL + schunk * 8;
  const bf16* Bg = W + (size_t)(nb + srow) * D_MODEL + schunk * 8;
  bf16* Al0 = &As[srow * 32 + schunk * 8];
  bf16* Al1 = &As[(srow + 64) * 32 + schunk * 8];
  bf16* Bl0 = &Bs[srow * 32 + schunk * 8];
  bf16* Bl1 = &Bs[(srow + 64) * 32 + schunk * 8];

  f32x4 acc[4][4];
#pragma unroll
  for (int i = 0; i < 4; ++i)
#pragma unroll
    for (int j = 0; j < 4; ++j) acc[i][j] = (f32x4){0.f, 0.f, 0.f, 0.f};

  for (int k0 = 0; k0 < D_MODEL; k0 += 32) {
    async_copy16(Ag + k0, Al0);
    async_copy16(Ag + k0 + (size_t)64 * D_MODEL, Al1);
    async_copy16(Bg + k0, Bl0);
    async_copy16(Bg + k0 + (size_t)64 * D_MODEL, Bl1);
    __syncthreads();

    bf16x8 af[4], bfr[4];
#pragma unroll
    for (int i = 0; i < 4; ++i)
      af[i] = *(const bf16x8*)&As[(wm * 64 + i * 16 + l15) * 32 + quad * 8];
#pragma unroll
    for (int j = 0; j < 4; ++j)
      bfr[j] = *(const bf16x8*)&Bs[(wn * 64 + j * 16 + l15) * 32 + quad * 8];
#pragma unroll
    for (int i = 0; i < 4; ++i)
#pragma unroll
      for (int j = 0; j < 4; ++j)
        acc[i][j] = __builtin_amdgcn_mfma_f32_16x16x32_bf16(af[i], bfr[j],
                                                            acc[i][j], 0, 0, 0);
    __syncthreads();
  }

  // C layout: col = lane&15, row = quad*4 + reg
#pragma unroll
  for (int i = 0; i < 4; ++i) {
    int row = row0 + wm * 64 + i * 16 + quad * 4;
#pragma unroll
    for (int j = 0; j < 4; ++j) {
      int col = nb + wn * 64 + j * 16 + l15;
#pragma unroll
      for (int r = 0; r < 4; ++r)
        Out[(size_t)(row + r) * D_MODEL + col] = (bf16)acc[i][j][r];
    }
  }
}

// ---------------------------------------------------------------------------
// 3. RoPE in place on Q and K
// ---------------------------------------------------------------------------
__global__ __launch_bounds__(256) void rope_kernel(
    bf16* __restrict__ Q, bf16* __restrict__ K, const int* __restrict__ pos) {
  int idx = blockIdx.x * 256 + threadIdx.x;
  int i = idx & 31;
  int h = (idx >> 5) & 15;
  int row = idx >> 9;
  int t = row & (T_SZ - 1);
  float p = (float)pos[t];
  float freq = expf(-(float)i * 0.28782313662425f);  // ln(1e4)/32
  float ang = p * freq;
  float s, c;
  sincosf(ang, &s, &c);
  size_t base = (size_t)row * D_MODEL + h * DH + 2 * i;
  float q1 = (float)Q[base], q2 = (float)Q[base + 1];
  Q[base]     = (bf16)(q1 * c - q2 * s);
  Q[base + 1] = (bf16)(q1 * s + q2 * c);
  float k1 = (float)K[base], k2 = (float)K[base + 1];
  K[base]     = (bf16)(k1 * c - k2 * s);
  K[base + 1] = (bf16)(k1 * s + k2 * c);
}

// ---------------------------------------------------------------------------
// 3b. V transpose: V (B*T, 1024) -> VT (B,H,DH,T) so PV B-frags are contiguous
// ---------------------------------------------------------------------------
__global__ __launch_bounds__(256) void v_transpose(
    const bf16* __restrict__ V, bf16* __restrict__ VT) {
  __shared__ bf16 tile[64][72];   // 72*2B = 144B rows -> 16B-aligned rows
  int bh = blockIdx.x;            // b*16+h
  int tt = blockIdx.y;            // t-tile of 64
  int b = bh >> 4, h = bh & 15;
  int tid = threadIdx.x;
  int rr = tid >> 3;              // 0..31
  int cc = (tid & 7) * 8;         // 0..56
#pragma unroll
  for (int p = 0; p < 2; ++p) {
    int t = rr + p * 32;
    bf16x8 v = *(const bf16x8*)&V[((size_t)b * T_SZ + tt * 64 + t) * D_MODEL +
                                  h * DH + cc];
    *(bf16x8*)&tile[t][cc] = v;
  }
  __syncthreads();
#pragma unroll
  for (int p = 0; p < 2; ++p) {
    int d = rr + p * 32;
    bf16x8 o;
#pragma unroll
    for (int j = 0; j < 8; ++j) o[j] = tile[cc + j][d];
    *(bf16x8*)&VT[((size_t)bh * DH + d) * T_SZ + tt * 64 + cc] = o;
  }
}

// ---------------------------------------------------------------------------
// 4. Causal flash attention. Block = (b*h, q-tile of 64). 4 waves x 16 rows.
// ---------------------------------------------------------------------------
__global__ __launch_bounds__(256) void attn_kernel(
    const bf16* __restrict__ Q, const bf16* __restrict__ K,
    const bf16* __restrict__ VT, bf16* __restrict__ AO) {
  __shared__ bf16 Pbuf[4][16 * 32];

  int bh = blockIdx.x;       // 0..31
  int qt = blockIdx.y;       // 0..31
  int bb = bh >> 4, h = bh & 15;
  int wave = threadIdx.x >> 6, lane = threadIdx.x & 63;
  int l15 = lane & 15, quad = lane >> 4;

  int q_local = qt * 64 + wave * 16;
  size_t grow0 = (size_t)bb * T_SZ + q_local;

  const bf16* Qbase = Q + (grow0 + l15) * D_MODEL + h * DH + quad * 8;
  bf16x8 aq0 = *(const bf16x8*)(Qbase);
  bf16x8 aq1 = *(const bf16x8*)(Qbase + 32);

  f32x4 o[4];
#pragma unroll
  for (int nt = 0; nt < 4; ++nt) o[nt] = (f32x4){0.f, 0.f, 0.f, 0.f};
  float m_i[4], l_i[4];
#pragma unroll
  for (int r = 0; r < 4; ++r) { m_i[r] = -1e30f; l_i[r] = 0.f; }

  bf16* Pw = Pbuf[wave];
  int ntiles = qt * 2 + 2;   // uniform across block

  for (int t = 0; t < ntiles; ++t) {
    int kv0 = t * 32;

    // ---- S = scale * Q K^T ----
    const bf16* Kb0 =
        K + ((size_t)bb * T_SZ + kv0 + l15) * D_MODEL + h * DH + quad * 8;
    const bf16* Kb1 = Kb0 + (size_t)16 * D_MODEL;
    f32x4 s0 = (f32x4){0.f, 0.f, 0.f, 0.f};
    f32x4 s1 = (f32x4){0.f, 0.f, 0.f, 0.f};
    {
      bf16x8 b00 = *(const bf16x8*)(Kb0);
      bf16x8 b01 = *(const bf16x8*)(Kb0 + 32);
      s0 = __builtin_amdgcn_mfma_f32_16x16x32_bf16(aq0, b00, s0, 0, 0, 0);
      s0 = __builtin_amdgcn_mfma_f32_16x16x32_bf16(aq1, b01, s0, 0, 0, 0);
      bf16x8 b10 = *(const bf16x8*)(Kb1);
      bf16x8 b11 = *(const bf16x8*)(Kb1 + 32);
      s1 = __builtin_amdgcn_mfma_f32_16x16x32_bf16(aq0, b10, s1, 0, 0, 0);
      s1 = __builtin_amdgcn_mfma_f32_16x16x32_bf16(aq1, b11, s1, 0, 0, 0);
    }

    // ---- scale + causal mask ----
    float vals[2][4];
#pragma unroll
    for (int ct = 0; ct < 2; ++ct) {
      int kc = kv0 + ct * 16 + l15;
#pragma unroll
      for (int r = 0; r < 4; ++r) {
        int qr = q_local + quad * 4 + r;
        float v = (ct == 0 ? s0[r] : s1[r]) * 0.125f;
        vals[ct][r] = (kc > qr) ? -1e30f : v;
      }
    }

    // ---- row max ----
    float mloc[4];
#pragma unroll
    for (int r = 0; r < 4; ++r) mloc[r] = fmaxf(vals[0][r], vals[1][r]);
#pragma unroll
    for (int off = 1; off < 16; off <<= 1) {
#pragma unroll
      for (int r = 0; r < 4; ++r)
        mloc[r] = fmaxf(mloc[r], __shfl_xor(mloc[r], off));
    }

    float alpha[4];
#pragma unroll
    for (int r = 0; r < 4; ++r) {
      float mn = fmaxf(m_i[r], mloc[r]);
      alpha[r] = __expf(m_i[r] - mn);
      m_i[r] = mn;
    }

    // ---- P = exp(S - m), row-sum ----
    float psum[4] = {0.f, 0.f, 0.f, 0.f};
#pragma unroll
    for (int ct = 0; ct < 2; ++ct)
#pragma unroll
      for (int r = 0; r < 4; ++r) {
        float p = __expf(vals[ct][r] - m_i[r]);
        vals[ct][r] = p;
        psum[r] += p;
      }
#pragma unroll
    for (int off = 1; off < 16; off <<= 1) {
#pragma unroll
      for (int r = 0; r < 4; ++r) psum[r] += __shfl_xor(psum[r], off);
    }
#pragma unroll
    for (int r = 0; r < 4; ++r) l_i[r] = l_i[r] * alpha[r] + psum[r];

#pragma unroll
    for (int nt = 0; nt < 4; ++nt)
#pragma unroll
      for (int r = 0; r < 4; ++r) o[nt][r] *= alpha[r];

    // ---- P (C-layout) -> LDS -> A-operand layout ----
#pragma unroll
    for (int ct = 0; ct < 2; ++ct)
#pragma unroll
      for (int r = 0; r < 4; ++r)
        Pw[(quad * 4 + r) * 32 + ct * 16 + l15] = (bf16)vals[ct][r];
    __syncthreads();
    bf16x8 ap = *(const bf16x8*)(Pw + l15 * 32 + quad * 8);

    // ---- O += P V   (B-frag from VT: contiguous bf16x8) ----
#pragma unroll
    for (int nt = 0; nt < 4; ++nt) {
      bf16x8 bv = *(const bf16x8*)&VT[((size_t)bh * DH + nt * 16 + l15) * T_SZ +
                                      kv0 + quad * 8];
      o[nt] = __builtin_amdgcn_mfma_f32_16x16x32_bf16(ap, bv, o[nt], 0, 0, 0);
    }
    __syncthreads();
  }

  float inv[4];
#pragma unroll
  for (int r = 0; r < 4; ++r) inv[r] = 1.0f / l_i[r];
#pragma unroll
  for (int nt = 0; nt < 4; ++nt)
#pragma unroll
    for (int r = 0; r < 4; ++r)
      AO[(grow0 + quad * 4 + r) * D_MODEL + h * DH + nt * 16 + l15] =
          (bf16)(o[nt][r] * inv[r]);
}

// ---------------------------------------------------------------------------
// 5. Output GEMM, m97 structure: out(m,n) = sum_k AO(m,k)*Wo(n,k), fp32 out
// ---------------------------------------------------------------------------
__global__ __launch_bounds__(256) void out_gemm(
    const bf16* __restrict__ AO, const bf16* __restrict__ Wob,
    float* __restrict__ out) {
  __shared__ bf16 As[128 * 32];
  __shared__ bf16 Bs[128 * 32];

  int tid = threadIdx.x;
  int wave = tid >> 6, lane = tid & 63;
  int wm = wave >> 1, wn = wave & 1;
  int l15 = lane & 15, quad = lane >> 4;

  int row0 = blockIdx.x * 128;
  int nb = blockIdx.y * 128;

  int srow = tid >> 2;
  int schunk = tid & 3;
  const bf16* Ag = AO + (size_t)(row0 + srow) * D_MODEL + schunk * 8;
  const bf16* Bg = Wob + (size_t)(nb + srow) * D_MODEL + schunk * 8;
  bf16* Al0 = &As[srow * 32 + schunk * 8];
  bf16* Al1 = &As[(srow + 64) * 32 + schunk * 8];
  bf16* Bl0 = &Bs[srow * 32 + schunk * 8];
  bf16* Bl1 = &Bs[(srow + 64) * 32 + schunk * 8];

  f32x4 acc[4][4];
#pragma unroll
  for (int i = 0; i < 4; ++i)
#pragma unroll
    for (int j = 0; j < 4; ++j) acc[i][j] = (f32x4){0.f, 0.f, 0.f, 0.f};

  for (int k0 = 0; k0 < D_MODEL; k0 += 32) {
    async_copy16(Ag + k0, Al0);
    async_copy16(Ag + k0 + (size_t)64 * D_MODEL, Al1);
    async_copy16(Bg + k0, Bl0);
    async_copy16(Bg + k0 + (size_t)64 * D_MODEL, Bl1);
    __syncthreads();

    bf16x8 af[4], bfr[4];
#pragma unroll
    for (int i = 0; i < 4; ++i)
      af[i] = *(const bf16x8*)&As[(wm * 64 + i * 16 + l15) * 32 + quad * 8];
#pragma unroll
    for (int j = 0; j < 4; ++j)
      bfr[j] = *(const bf16x8*)&Bs[(wn * 64 + j * 16 + l15) * 32 + quad * 8];
#pragma unroll
    for (int i = 0; i < 4; ++i)
#pragma unroll
      for (int j = 0; j < 4; ++j)
        acc[i][j] = __builtin_amdgcn_mfma_f32_16x16x32_bf16(af[i], bfr[j],
                                                            acc[i][j], 0, 0, 0);
    __syncthreads();
  }

#pragma unroll
  for (int i = 0; i < 4; ++i) {
    int row = row0 + wm * 64 + i * 16 + quad * 4;
#pragma unroll
    for (int j = 0; j < 4; ++j) {
      int col = nb + wn * 64 + j * 16 + l15;
#pragma unroll
      for (int r = 0; r < 4; ++r)
        out[(size_t)(row + r) * D_MODEL + col] = acc[i][j][r];
    }
  }
}

// ---------------------------------------------------------------------------
extern "C" void kernel_launch(void* const* d_in, const int* in_sizes, int n_in,
                              void* d_out, int out_size, void* d_ws, size_t ws_size,
                              hipStream_t stream) {
  const float* X  = (const float*)d_in[0];
  const float* Wq = (const float*)d_in[1];
  const float* Wk = (const float*)d_in[2];
  const float* Wv = (const float*)d_in[3];
  const float* Wo = (const float*)d_in[4];
  const int*  pos = (const int*)d_in[5];
  float* out = (float*)d_out;

  char* w = (char*)d_ws;
  bf16* Xb  = (bf16*)w;  w += (size_t)M_ROWS * D_MODEL * 2;   // 8 MB
  bf16* Wqb = (bf16*)w;  w += (size_t)D_MODEL * D_MODEL * 2;  // 2 MB
  bf16* Wkb = (bf16*)w;  w += (size_t)D_MODEL * D_MODEL * 2;
  bf16* Wvb = (bf16*)w;  w += (size_t)D_MODEL * D_MODEL * 2;
  bf16* Wob = (bf16*)w;  w += (size_t)D_MODEL * D_MODEL * 2;
  bf16* Qb  = (bf16*)w;  w += (size_t)M_ROWS * D_MODEL * 2;
  bf16* Kb  = (bf16*)w;  w += (size_t)M_ROWS * D_MODEL * 2;
  bf16* Vb  = (bf16*)w;  w += (size_t)M_ROWS * D_MODEL * 2;
  bf16* AO  = (bf16*)w;  w += (size_t)M_ROWS * D_MODEL * 2;
  bf16* VT  = (bf16*)w;  w += (size_t)M_ROWS * D_MODEL * 2;   // (B,H,DH,T)

  cast_all<<<(NX + 4 * NW) / 256, 256, 0, stream>>>(X, Wq, Wk, Wv, Wo,
                                                    Xb, Wqb, Wkb, Wvb, Wob);
  qkv_gemm<<<dim3(M_ROWS / 128, 3 * D_MODEL / 128), 256, 0, stream>>>(
      Xb, Wqb, Wkb, Wvb, Qb, Kb, Vb);
  rope_kernel<<<(M_ROWS * NUM_HEADS * 32) / 256, 256, 0, stream>>>(Qb, Kb, pos);
  v_transpose<<<dim3(B_SZ * NUM_HEADS, T_SZ / 64), 256, 0, stream>>>(Vb, VT);
  attn_kernel<<<dim3(B_SZ * NUM_HEADS, T_SZ / 64), 256, 0, stream>>>(Qb, Kb, VT, AO);
  out_gemm<<<dim3(M_ROWS / 128, D_MODEL / 128), 256, 0, stream>>>(AO, Wob, out);
}

// Round 3
// 296.757 us; speedup vs baseline: 1.8080x; 1.0557x over previous
//
#include <hip/hip_runtime.h>

#define D_MODEL 1024
#define NUM_HEADS 16
#define DH 64
#define B_SZ 2
#define T_SZ 2048
#define M_ROWS (B_SZ * T_SZ)   // 4096

typedef __bf16 bf16;
typedef __bf16 bf16x4 __attribute__((ext_vector_type(4)));
typedef __bf16 bf16x8 __attribute__((ext_vector_type(8)));
typedef float f32x4 __attribute__((ext_vector_type(4)));

__device__ __forceinline__ void async_copy16(const bf16* g, bf16* l) {
  __builtin_amdgcn_global_load_lds(
      (const __attribute__((address_space(1))) void*)g,
      (__attribute__((address_space(3))) void*)l, 16, 0, 0);
}

// ---------------------------------------------------------------------------
// 1. Cast fp32 -> bf16
// ---------------------------------------------------------------------------
#define NX (M_ROWS * D_MODEL / 4)
#define NW (D_MODEL * D_MODEL / 4)

__global__ __launch_bounds__(256) void cast_all(
    const float* __restrict__ X, const float* __restrict__ Wq,
    const float* __restrict__ Wk, const float* __restrict__ Wv,
    const float* __restrict__ Wo,
    bf16* __restrict__ Xb, bf16* __restrict__ Wqb, bf16* __restrict__ Wkb,
    bf16* __restrict__ Wvb, bf16* __restrict__ Wob) {
  int i = blockIdx.x * 256 + threadIdx.x;
  const float* s; bf16* d; int off;
  if (i < NX) {
    s = X; d = Xb; off = i;
  } else {
    int j = i - NX;
    int w = j >> 18;
    off = j & (NW - 1);
    if (w == 0)      { s = Wq; d = Wqb; }
    else if (w == 1) { s = Wk; d = Wkb; }
    else if (w == 2) { s = Wv; d = Wvb; }
    else             { s = Wo; d = Wob; }
  }
  float4 v = ((const float4*)s)[off];
  bf16x4 o;
  o[0] = (bf16)v.x; o[1] = (bf16)v.y; o[2] = (bf16)v.z; o[3] = (bf16)v.w;
  ((bf16x4*)d)[off] = o;
}

// ---------------------------------------------------------------------------
// 2. QKV GEMM, m97 structure (unchanged from R1)
// ---------------------------------------------------------------------------
__global__ __launch_bounds__(256) void qkv_gemm(
    const bf16* __restrict__ Xb,
    const bf16* __restrict__ Wqb, const bf16* __restrict__ Wkb,
    const bf16* __restrict__ Wvb,
    bf16* __restrict__ Q, bf16* __restrict__ K, bf16* __restrict__ V) {
  __shared__ bf16 As[128 * 32];
  __shared__ bf16 Bs[128 * 32];

  int tid = threadIdx.x;
  int wave = tid >> 6, lane = tid & 63;
  int wm = wave >> 1, wn = wave & 1;
  int l15 = lane & 15, quad = lane >> 4;

  int row0 = blockIdx.x * 128;
  int col0 = blockIdx.y * 128;
  int sel = col0 >> 10;
  int nb = col0 & 1023;
  const bf16* W; bf16* Out;
  if (sel == 0)      { W = Wqb; Out = Q; }
  else if (sel == 1) { W = Wkb; Out = K; }
  else               { W = Wvb; Out = V; }

  int srow = tid >> 2;
  int schunk = tid & 3;
  const bf16* Ag = Xb + (size_t)(row0 + srow) * D_MODEL + schunk * 8;
  const bf16* Bg = W + (size_t)(nb + srow) * D_MODEL + schunk * 8;
  bf16* Al0 = &As[srow * 32 + schunk * 8];
  bf16* Al1 = &As[(srow + 64) * 32 + schunk * 8];
  bf16* Bl0 = &Bs[srow * 32 + schunk * 8];
  bf16* Bl1 = &Bs[(srow + 64) * 32 + schunk * 8];

  f32x4 acc[4][4];
#pragma unroll
  for (int i = 0; i < 4; ++i)
#pragma unroll
    for (int j = 0; j < 4; ++j) acc[i][j] = (f32x4){0.f, 0.f, 0.f, 0.f};

  for (int k0 = 0; k0 < D_MODEL; k0 += 32) {
    async_copy16(Ag + k0, Al0);
    async_copy16(Ag + k0 + (size_t)64 * D_MODEL, Al1);
    async_copy16(Bg + k0, Bl0);
    async_copy16(Bg + k0 + (size_t)64 * D_MODEL, Bl1);
    __syncthreads();

    bf16x8 af[4], bfr[4];
#pragma unroll
    for (int i = 0; i < 4; ++i)
      af[i] = *(const bf16x8*)&As[(wm * 64 + i * 16 + l15) * 32 + quad * 8];
#pragma unroll
    for (int j = 0; j < 4; ++j)
      bfr[j] = *(const bf16x8*)&Bs[(wn * 64 + j * 16 + l15) * 32 + quad * 8];
#pragma unroll
    for (int i = 0; i < 4; ++i)
#pragma unroll
      for (int j = 0; j < 4; ++j)
        acc[i][j] = __builtin_amdgcn_mfma_f32_16x16x32_bf16(af[i], bfr[j],
                                                            acc[i][j], 0, 0, 0);
    __syncthreads();
  }

#pragma unroll
  for (int i = 0; i < 4; ++i) {
    int row = row0 + wm * 64 + i * 16 + quad * 4;
#pragma unroll
    for (int j = 0; j < 4; ++j) {
      int col = nb + wn * 64 + j * 16 + l15;
#pragma unroll
      for (int r = 0; r < 4; ++r)
        Out[(size_t)(row + r) * D_MODEL + col] = (bf16)acc[i][j][r];
    }
  }
}

// ---------------------------------------------------------------------------
// 3. RoPE in place on Q and K
// ---------------------------------------------------------------------------
__global__ __launch_bounds__(256) void rope_kernel(
    bf16* __restrict__ Q, bf16* __restrict__ K, const int* __restrict__ pos) {
  int idx = blockIdx.x * 256 + threadIdx.x;
  int i = idx & 31;
  int h = (idx >> 5) & 15;
  int row = idx >> 9;
  int t = row & (T_SZ - 1);
  float p = (float)pos[t];
  float freq = expf(-(float)i * 0.28782313662425f);
  float ang = p * freq;
  float s, c;
  sincosf(ang, &s, &c);
  size_t base = (size_t)row * D_MODEL + h * DH + 2 * i;
  float q1 = (float)Q[base], q2 = (float)Q[base + 1];
  Q[base]     = (bf16)(q1 * c - q2 * s);
  Q[base + 1] = (bf16)(q1 * s + q2 * c);
  float k1 = (float)K[base], k2 = (float)K[base + 1];
  K[base]     = (bf16)(k1 * c - k2 * s);
  K[base + 1] = (bf16)(k1 * s + k2 * c);
}

// ---------------------------------------------------------------------------
// 3b. V transpose: V (B*T, 1024) -> VT (B,H,DH,T)
// ---------------------------------------------------------------------------
__global__ __launch_bounds__(256) void v_transpose(
    const bf16* __restrict__ V, bf16* __restrict__ VT) {
  __shared__ bf16 tile[64][72];
  int bh = blockIdx.x;
  int tt = blockIdx.y;
  int b = bh >> 4, h = bh & 15;
  int tid = threadIdx.x;
  int rr = tid >> 3;
  int cc = (tid & 7) * 8;
#pragma unroll
  for (int p = 0; p < 2; ++p) {
    int t = rr + p * 32;
    bf16x8 v = *(const bf16x8*)&V[((size_t)b * T_SZ + tt * 64 + t) * D_MODEL +
                                  h * DH + cc];
    *(bf16x8*)&tile[t][cc] = v;
  }
  __syncthreads();
#pragma unroll
  for (int p = 0; p < 2; ++p) {
    int d = rr + p * 32;
    bf16x8 o;
#pragma unroll
    for (int j = 0; j < 8; ++j) o[j] = tile[cc + j][d];
    *(bf16x8*)&VT[((size_t)bh * DH + d) * T_SZ + tt * 64 + cc] = o;
  }
}

// ---------------------------------------------------------------------------
// 4. Causal flash attention, S^T formulation.
//    Block = (bh, qt). Wave w owns q-rows [qt*64+w*16, +16); kv chunks of 64.
//    S^T = K·Q^T  (A=K-frag, B=Q-frag) -> per-lane scalar softmax state.
//    O^T = V^T·P^T (A=VT-frag, B=P read from per-wave LDS). No block barriers.
// ---------------------------------------------------------------------------
#define PSTRIDE 80

__global__ __launch_bounds__(256) void attn_kernel(
    const bf16* __restrict__ Q, const bf16* __restrict__ K,
    const bf16* __restrict__ VT, bf16* __restrict__ AO) {
  __shared__ bf16 Pbuf[4][16 * PSTRIDE];

  int bh = blockIdx.x;                 // 0..31
  int qt = (T_SZ / 64 - 1) - blockIdx.y;  // heavy blocks dispatched first
  int bb = bh >> 4, h = bh & 15;
  int wave = threadIdx.x >> 6, lane = threadIdx.x & 63;
  int l15 = lane & 15, quad = lane >> 4;

  int q0 = qt * 64 + wave * 16;        // wave's q-tile base
  size_t grow = (size_t)bb * T_SZ + q0;

  // Q B-frags: B[k][n], n = l15 = q, k = quad*8+j (+32)
  const bf16* Qp = Q + (grow + l15) * D_MODEL + h * DH + quad * 8;
  bf16x8 bq0 = *(const bf16x8*)(Qp);
  bf16x8 bq1 = *(const bf16x8*)(Qp + 32);

  f32x4 o[4];                          // O^T: 4 d-subtiles, col=q=l15
#pragma unroll
  for (int nt = 0; nt < 4; ++nt) o[nt] = (f32x4){0.f, 0.f, 0.f, 0.f};
  float m_i = -1e30f, l_i = 0.f;       // per-lane (per-q) scalars

  bf16* Pw = Pbuf[wave];
  const bf16* Kbase = K + ((size_t)bb * T_SZ) * D_MODEL + h * DH + quad * 8;
  const bf16* Vbase = VT + ((size_t)bh * DH) * T_SZ;
  int nchunks = qt + 1;

  for (int t = 0; t < nchunks; ++t) {
    int kv0 = t * 64;

    // ---- S^T = K · Q^T : 4 c-subtiles x (DH=64 -> 2 k-frags) ----
    f32x4 st[4];
#pragma unroll
    for (int cs = 0; cs < 4; ++cs) {
      const bf16* Kp = Kbase + (size_t)(kv0 + cs * 16 + l15) * D_MODEL;
      bf16x8 ak0 = *(const bf16x8*)(Kp);
      bf16x8 ak1 = *(const bf16x8*)(Kp + 32);
      f32x4 s = (f32x4){0.f, 0.f, 0.f, 0.f};
      s = __builtin_amdgcn_mfma_f32_16x16x32_bf16(ak0, bq0, s, 0, 0, 0);
      s = __builtin_amdgcn_mfma_f32_16x16x32_bf16(ak1, bq1, s, 0, 0, 0);
      st[cs] = s;
    }

    // ---- scale (+ causal mask on last chunk only) ----
    if (t == nchunks - 1) {
      // c_local = cs*16 + quad*4 + r ; q_local = wave*16 + l15
      int ql = wave * 16 + l15;
#pragma unroll
      for (int cs = 0; cs < 4; ++cs)
#pragma unroll
        for (int r = 0; r < 4; ++r) {
          int cl = cs * 16 + quad * 4 + r;
          st[cs][r] = (cl > ql) ? -1e30f : st[cs][r] * 0.125f;
        }
    } else {
#pragma unroll
      for (int cs = 0; cs < 4; ++cs)
#pragma unroll
        for (int r = 0; r < 4; ++r) st[cs][r] *= 0.125f;
    }

    // ---- per-lane max over 16 regs, then across 4 quads ----
    float mloc = st[0][0];
#pragma unroll
    for (int cs = 0; cs < 4; ++cs)
#pragma unroll
      for (int r = 0; r < 4; ++r) mloc = fmaxf(mloc, st[cs][r]);
    mloc = fmaxf(mloc, __shfl_xor(mloc, 16));
    mloc = fmaxf(mloc, __shfl_xor(mloc, 32));

    float mn = fmaxf(m_i, mloc);
    float alpha = __expf(m_i - mn);
    m_i = mn;

    // ---- P = exp(S - m), per-lane sum, cross-quad sum ----
    float psum = 0.f;
#pragma unroll
    for (int cs = 0; cs < 4; ++cs)
#pragma unroll
      for (int r = 0; r < 4; ++r) {
        float p = __expf(st[cs][r] - mn);
        st[cs][r] = p;
        psum += p;
      }
    psum += __shfl_xor(psum, 16);
    psum += __shfl_xor(psum, 32);
    l_i = l_i * alpha + psum;

#pragma unroll
    for (int nt = 0; nt < 4; ++nt)
#pragma unroll
      for (int r = 0; r < 4; ++r) o[nt][r] *= alpha;

    // ---- P[q][c] to per-wave LDS: packed b64 writes, no barrier ----
#pragma unroll
    for (int cs = 0; cs < 4; ++cs) {
      bf16x4 pk;
#pragma unroll
      for (int r = 0; r < 4; ++r) pk[r] = (bf16)st[cs][r];
      *(bf16x4*)&Pw[l15 * PSTRIDE + cs * 16 + quad * 4] = pk;
    }
    // same-wave DS ops are in-order in HW; stop compiler reordering only
    __asm__ __volatile__("" ::: "memory");
    __builtin_amdgcn_sched_barrier(0);

    bf16x8 bp0 = *(const bf16x8*)&Pw[l15 * PSTRIDE + quad * 8];
    bf16x8 bp1 = *(const bf16x8*)&Pw[l15 * PSTRIDE + 32 + quad * 8];
    __builtin_amdgcn_sched_barrier(0);

    // ---- O^T += V^T · P^T ----
#pragma unroll
    for (int nt = 0; nt < 4; ++nt) {
      const bf16* Vp = Vbase + (size_t)(nt * 16 + l15) * T_SZ + kv0 + quad * 8;
      bf16x8 av0 = *(const bf16x8*)(Vp);
      bf16x8 av1 = *(const bf16x8*)(Vp + 32);
      o[nt] = __builtin_amdgcn_mfma_f32_16x16x32_bf16(av0, bp0, o[nt], 0, 0, 0);
      o[nt] = __builtin_amdgcn_mfma_f32_16x16x32_bf16(av1, bp1, o[nt], 0, 0, 0);
    }
    __asm__ __volatile__("" ::: "memory");
  }

  // ---- epilogue: O[q][d] = O^T / l ; q=l15, d = nt*16+quad*4+r ----
  float inv = 1.0f / l_i;
#pragma unroll
  for (int nt = 0; nt < 4; ++nt) {
    bf16x4 ov;
#pragma unroll
    for (int r = 0; r < 4; ++r) ov[r] = (bf16)(o[nt][r] * inv);
    *(bf16x4*)&AO[(grow + l15) * D_MODEL + h * DH + nt * 16 + quad * 4] = ov;
  }
}

// ---------------------------------------------------------------------------
// 5. Output GEMM, m97 structure (unchanged from R1)
// ---------------------------------------------------------------------------
__global__ __launch_bounds__(256) void out_gemm(
    const bf16* __restrict__ AO, const bf16* __restrict__ Wob,
    float* __restrict__ out) {
  __shared__ bf16 As[128 * 32];
  __shared__ bf16 Bs[128 * 32];

  int tid = threadIdx.x;
  int wave = tid >> 6, lane = tid & 63;
  int wm = wave >> 1, wn = wave & 1;
  int l15 = lane & 15, quad = lane >> 4;

  int row0 = blockIdx.x * 128;
  int nb = blockIdx.y * 128;

  int srow = tid >> 2;
  int schunk = tid & 3;
  const bf16* Ag = AO + (size_t)(row0 + srow) * D_MODEL + schunk * 8;
  const bf16* Bg = Wob + (size_t)(nb + srow) * D_MODEL + schunk * 8;
  bf16* Al0 = &As[srow * 32 + schunk * 8];
  bf16* Al1 = &As[(srow + 64) * 32 + schunk * 8];
  bf16* Bl0 = &Bs[srow * 32 + schunk * 8];
  bf16* Bl1 = &Bs[(srow + 64) * 32 + schunk * 8];

  f32x4 acc[4][4];
#pragma unroll
  for (int i = 0; i < 4; ++i)
#pragma unroll
    for (int j = 0; j < 4; ++j) acc[i][j] = (f32x4){0.f, 0.f, 0.f, 0.f};

  for (int k0 = 0; k0 < D_MODEL; k0 += 32) {
    async_copy16(Ag + k0, Al0);
    async_copy16(Ag + k0 + (size_t)64 * D_MODEL, Al1);
    async_copy16(Bg + k0, Bl0);
    async_copy16(Bg + k0 + (size_t)64 * D_MODEL, Bl1);
    __syncthreads();

    bf16x8 af[4], bfr[4];
#pragma unroll
    for (int i = 0; i < 4; ++i)
      af[i] = *(const bf16x8*)&As[(wm * 64 + i * 16 + l15) * 32 + quad * 8];
#pragma unroll
    for (int j = 0; j < 4; ++j)
      bfr[j] = *(const bf16x8*)&Bs[(wn * 64 + j * 16 + l15) * 32 + quad * 8];
#pragma unroll
    for (int i = 0; i < 4; ++i)
#pragma unroll
      for (int j = 0; j < 4; ++j)
        acc[i][j] = __builtin_amdgcn_mfma_f32_16x16x32_bf16(af[i], bfr[j],
                                                            acc[i][j], 0, 0, 0);
    __syncthreads();
  }

#pragma unroll
  for (int i = 0; i < 4; ++i) {
    int row = row0 + wm * 64 + i * 16 + quad * 4;
#pragma unroll
    for (int j = 0; j < 4; ++j) {
      int col = nb + wn * 64 + j * 16 + l15;
#pragma unroll
      for (int r = 0; r < 4; ++r)
        out[(size_t)(row + r) * D_MODEL + col] = acc[i][j][r];
    }
  }
}

// ---------------------------------------------------------------------------
extern "C" void kernel_launch(void* const* d_in, const int* in_sizes, int n_in,
                              void* d_out, int out_size, void* d_ws, size_t ws_size,
                              hipStream_t stream) {
  const float* X  = (const float*)d_in[0];
  const float* Wq = (const float*)d_in[1];
  const float* Wk = (const float*)d_in[2];
  const float* Wv = (const float*)d_in[3];
  const float* Wo = (const float*)d_in[4];
  const int*  pos = (const int*)d_in[5];
  float* out = (float*)d_out;

  char* w = (char*)d_ws;
  bf16* Xb  = (bf16*)w;  w += (size_t)M_ROWS * D_MODEL * 2;
  bf16* Wqb = (bf16*)w;  w += (size_t)D_MODEL * D_MODEL * 2;
  bf16* Wkb = (bf16*)w;  w += (size_t)D_MODEL * D_MODEL * 2;
  bf16* Wvb = (bf16*)w;  w += (size_t)D_MODEL * D_MODEL * 2;
  bf16* Wob = (bf16*)w;  w += (size_t)D_MODEL * D_MODEL * 2;
  bf16* Qb  = (bf16*)w;  w += (size_t)M_ROWS * D_MODEL * 2;
  bf16* Kb  = (bf16*)w;  w += (size_t)M_ROWS * D_MODEL * 2;
  bf16* Vb  = (bf16*)w;  w += (size_t)M_ROWS * D_MODEL * 2;
  bf16* AO  = (bf16*)w;  w += (size_t)M_ROWS * D_MODEL * 2;
  bf16* VT  = (bf16*)w;  w += (size_t)M_ROWS * D_MODEL * 2;

  cast_all<<<(NX + 4 * NW) / 256, 256, 0, stream>>>(X, Wq, Wk, Wv, Wo,
                                                    Xb, Wqb, Wkb, Wvb, Wob);
  qkv_gemm<<<dim3(M_ROWS / 128, 3 * D_MODEL / 128), 256, 0, stream>>>(
      Xb, Wqb, Wkb, Wvb, Qb, Kb, Vb);
  rope_kernel<<<(M_ROWS * NUM_HEADS * 32) / 256, 256, 0, stream>>>(Qb, Kb, pos);
  v_transpose<<<dim3(B_SZ * NUM_HEADS, T_SZ / 64), 256, 0, stream>>>(Vb, VT);
  attn_kernel<<<dim3(B_SZ * NUM_HEADS, T_SZ / 64), 256, 0, stream>>>(Qb, Kb, VT, AO);
  out_gemm<<<dim3(M_ROWS / 128, D_MODEL / 128), 256, 0, stream>>>(AO, Wob, out);
}

// Round 4
// 274.714 us; speedup vs baseline: 1.9531x; 1.0802x over previous
//
#include <hip/hip_runtime.h>

#define D_MODEL 1024
#define NUM_HEADS 16
#define DH 64
#define B_SZ 2
#define T_SZ 2048
#define M_ROWS (B_SZ * T_SZ)   // 4096

typedef __bf16 bf16;
typedef __bf16 bf16x4 __attribute__((ext_vector_type(4)));
typedef __bf16 bf16x8 __attribute__((ext_vector_type(8)));
typedef float f32x4 __attribute__((ext_vector_type(4)));

__device__ __forceinline__ void async_copy16(const bf16* g, bf16* l) {
  __builtin_amdgcn_global_load_lds(
      (const __attribute__((address_space(1))) void*)g,
      (__attribute__((address_space(3))) void*)l, 16, 0, 0);
}

// ---------------------------------------------------------------------------
// 1. Cast fp32 -> bf16
// ---------------------------------------------------------------------------
#define NX (M_ROWS * D_MODEL / 4)
#define NW (D_MODEL * D_MODEL / 4)

__global__ __launch_bounds__(256) void cast_all(
    const float* __restrict__ X, const float* __restrict__ Wq,
    const float* __restrict__ Wk, const float* __restrict__ Wv,
    const float* __restrict__ Wo,
    bf16* __restrict__ Xb, bf16* __restrict__ Wqb, bf16* __restrict__ Wkb,
    bf16* __restrict__ Wvb, bf16* __restrict__ Wob) {
  int i = blockIdx.x * 256 + threadIdx.x;
  const float* s; bf16* d; int off;
  if (i < NX) {
    s = X; d = Xb; off = i;
  } else {
    int j = i - NX;
    int w = j >> 18;
    off = j & (NW - 1);
    if (w == 0)      { s = Wq; d = Wqb; }
    else if (w == 1) { s = Wk; d = Wkb; }
    else if (w == 2) { s = Wv; d = Wvb; }
    else             { s = Wo; d = Wob; }
  }
  float4 v = ((const float4*)s)[off];
  bf16x4 o;
  o[0] = (bf16)v.x; o[1] = (bf16)v.y; o[2] = (bf16)v.z; o[3] = (bf16)v.w;
  ((bf16x4*)d)[off] = o;
}

// ---------------------------------------------------------------------------
// 2. QKV GEMM, m97 structure (unchanged)
// ---------------------------------------------------------------------------
__global__ __launch_bounds__(256) void qkv_gemm(
    const bf16* __restrict__ Xb,
    const bf16* __restrict__ Wqb, const bf16* __restrict__ Wkb,
    const bf16* __restrict__ Wvb,
    bf16* __restrict__ Q, bf16* __restrict__ K, bf16* __restrict__ V) {
  __shared__ bf16 As[128 * 32];
  __shared__ bf16 Bs[128 * 32];

  int tid = threadIdx.x;
  int wave = tid >> 6, lane = tid & 63;
  int wm = wave >> 1, wn = wave & 1;
  int l15 = lane & 15, quad = lane >> 4;

  int row0 = blockIdx.x * 128;
  int col0 = blockIdx.y * 128;
  int sel = col0 >> 10;
  int nb = col0 & 1023;
  const bf16* W; bf16* Out;
  if (sel == 0)      { W = Wqb; Out = Q; }
  else if (sel == 1) { W = Wkb; Out = K; }
  else               { W = Wvb; Out = V; }

  int srow = tid >> 2;
  int schunk = tid & 3;
  const bf16* Ag = Xb + (size_t)(row0 + srow) * D_MODEL + schunk * 8;
  const bf16* Bg = W + (size_t)(nb + srow) * D_MODEL + schunk * 8;
  bf16* Al0 = &As[srow * 32 + schunk * 8];
  bf16* Al1 = &As[(srow + 64) * 32 + schunk * 8];
  bf16* Bl0 = &Bs[srow * 32 + schunk * 8];
  bf16* Bl1 = &Bs[(srow + 64) * 32 + schunk * 8];

  f32x4 acc[4][4];
#pragma unroll
  for (int i = 0; i < 4; ++i)
#pragma unroll
    for (int j = 0; j < 4; ++j) acc[i][j] = (f32x4){0.f, 0.f, 0.f, 0.f};

  for (int k0 = 0; k0 < D_MODEL; k0 += 32) {
    async_copy16(Ag + k0, Al0);
    async_copy16(Ag + k0 + (size_t)64 * D_MODEL, Al1);
    async_copy16(Bg + k0, Bl0);
    async_copy16(Bg + k0 + (size_t)64 * D_MODEL, Bl1);
    __syncthreads();

    bf16x8 af[4], bfr[4];
#pragma unroll
    for (int i = 0; i < 4; ++i)
      af[i] = *(const bf16x8*)&As[(wm * 64 + i * 16 + l15) * 32 + quad * 8];
#pragma unroll
    for (int j = 0; j < 4; ++j)
      bfr[j] = *(const bf16x8*)&Bs[(wn * 64 + j * 16 + l15) * 32 + quad * 8];
#pragma unroll
    for (int i = 0; i < 4; ++i)
#pragma unroll
      for (int j = 0; j < 4; ++j)
        acc[i][j] = __builtin_amdgcn_mfma_f32_16x16x32_bf16(af[i], bfr[j],
                                                            acc[i][j], 0, 0, 0);
    __syncthreads();
  }

#pragma unroll
  for (int i = 0; i < 4; ++i) {
    int row = row0 + wm * 64 + i * 16 + quad * 4;
#pragma unroll
    for (int j = 0; j < 4; ++j) {
      int col = nb + wn * 64 + j * 16 + l15;
#pragma unroll
      for (int r = 0; r < 4; ++r)
        Out[(size_t)(row + r) * D_MODEL + col] = (bf16)acc[i][j][r];
    }
  }
}

// ---------------------------------------------------------------------------
// 3. RoPE in place on Q and K
// ---------------------------------------------------------------------------
__global__ __launch_bounds__(256) void rope_kernel(
    bf16* __restrict__ Q, bf16* __restrict__ K, const int* __restrict__ pos) {
  int idx = blockIdx.x * 256 + threadIdx.x;
  int i = idx & 31;
  int h = (idx >> 5) & 15;
  int row = idx >> 9;
  int t = row & (T_SZ - 1);
  float p = (float)pos[t];
  float freq = expf(-(float)i * 0.28782313662425f);
  float ang = p * freq;
  float s, c;
  sincosf(ang, &s, &c);
  size_t base = (size_t)row * D_MODEL + h * DH + 2 * i;
  float q1 = (float)Q[base], q2 = (float)Q[base + 1];
  Q[base]     = (bf16)(q1 * c - q2 * s);
  Q[base + 1] = (bf16)(q1 * s + q2 * c);
  float k1 = (float)K[base], k2 = (float)K[base + 1];
  K[base]     = (bf16)(k1 * c - k2 * s);
  K[base + 1] = (bf16)(k1 * s + k2 * c);
}

// ---------------------------------------------------------------------------
// 3b. V transpose: V (B*T, 1024) -> VT (B,H,DH,T)
// ---------------------------------------------------------------------------
__global__ __launch_bounds__(256) void v_transpose(
    const bf16* __restrict__ V, bf16* __restrict__ VT) {
  __shared__ bf16 tile[64][72];
  int bh = blockIdx.x;
  int tt = blockIdx.y;
  int b = bh >> 4, h = bh & 15;
  int tid = threadIdx.x;
  int rr = tid >> 3;
  int cc = (tid & 7) * 8;
#pragma unroll
  for (int p = 0; p < 2; ++p) {
    int t = rr + p * 32;
    bf16x8 v = *(const bf16x8*)&V[((size_t)b * T_SZ + tt * 64 + t) * D_MODEL +
                                  h * DH + cc];
    *(bf16x8*)&tile[t][cc] = v;
  }
  __syncthreads();
#pragma unroll
  for (int p = 0; p < 2; ++p) {
    int d = rr + p * 32;
    bf16x8 o;
#pragma unroll
    for (int j = 0; j < 8; ++j) o[j] = tile[cc + j][d];
    *(bf16x8*)&VT[((size_t)bh * DH + d) * T_SZ + tt * 64 + cc] = o;
  }
}

// ---------------------------------------------------------------------------
// 4. Causal flash attention, S^T formulation, no-running-max softmax.
//    Block = 1 wave (64 thr). Wave owns 16 q-rows; kv chunks of 64.
//    O_unnorm += exp(S)·V, l += sum(exp(S)); normalize once at the end.
//    K double-buffered in registers; V loaded early; minimal LDS fences.
// ---------------------------------------------------------------------------
#define PST 72

__global__ __launch_bounds__(64) void attn_kernel(
    const bf16* __restrict__ Q, const bf16* __restrict__ K,
    const bf16* __restrict__ VT, bf16* __restrict__ AO) {
  __shared__ bf16 Pw[16 * PST];

  int bh = blockIdx.x;                    // 0..31
  int qi = 127 - (int)blockIdx.y;         // heavy q-tiles first
  int bb = bh >> 4, h = bh & 15;
  int lane = threadIdx.x & 63;
  int l15 = lane & 15, quad = lane >> 4;

  int q0 = qi * 16;
  size_t grow = (size_t)bb * T_SZ + q0;

  const bf16* Qp = Q + (grow + l15) * D_MODEL + h * DH + quad * 8;
  bf16x8 bq0 = *(const bf16x8*)(Qp);
  bf16x8 bq1 = *(const bf16x8*)(Qp + 32);

  f32x4 o[4];
#pragma unroll
  for (int nt = 0; nt < 4; ++nt) o[nt] = (f32x4){0.f, 0.f, 0.f, 0.f};
  float l_i = 0.f;

  const bf16* Kbase = K + ((size_t)bb * T_SZ) * D_MODEL + h * DH + quad * 8;
  const bf16* Vbase = VT + ((size_t)bh * DH) * T_SZ;
  int nchunks = qi / 4 + 1;
  int rel = (qi & 3) * 16 + l15;          // causal boundary in last chunk

  bf16x8 ka0[4], ka1[4], kb0[4], kb1[4];
#pragma unroll
  for (int cs = 0; cs < 4; ++cs) {
    const bf16* Kp = Kbase + (size_t)(cs * 16 + l15) * D_MODEL;
    ka0[cs] = *(const bf16x8*)Kp;
    ka1[cs] = *(const bf16x8*)(Kp + 32);
  }

  auto body = [&](bf16x8 (&kc0)[4], bf16x8 (&kc1)[4],
                  bf16x8 (&kn0)[4], bf16x8 (&kn1)[4], int t) {
    int kv0 = t * 64;
    bool last = (t == nchunks - 1);

    // ---- S^T = K · Q^T ----
    f32x4 st[4];
#pragma unroll
    for (int cs = 0; cs < 4; ++cs) {
      f32x4 s = (f32x4){0.f, 0.f, 0.f, 0.f};
      s = __builtin_amdgcn_mfma_f32_16x16x32_bf16(kc0[cs], bq0, s, 0, 0, 0);
      s = __builtin_amdgcn_mfma_f32_16x16x32_bf16(kc1[cs], bq1, s, 0, 0, 0);
      st[cs] = s;
    }

    // ---- prefetch next chunk's K into the other buffer ----
    if (!last) {
#pragma unroll
      for (int cs = 0; cs < 4; ++cs) {
        const bf16* Kp = Kbase + (size_t)(kv0 + 64 + cs * 16 + l15) * D_MODEL;
        kn0[cs] = *(const bf16x8*)Kp;
        kn1[cs] = *(const bf16x8*)(Kp + 32);
      }
    }

    // ---- V fragments for this chunk (issued early; used after LDS trip) ----
    bf16x8 av0[4], av1[4];
#pragma unroll
    for (int nt = 0; nt < 4; ++nt) {
      const bf16* Vp = Vbase + (size_t)(nt * 16 + l15) * T_SZ + kv0 + quad * 8;
      av0[nt] = *(const bf16x8*)(Vp);
      av1[nt] = *(const bf16x8*)(Vp + 32);
    }

    // ---- p = exp(s * scale); mask to 0 above diagonal; lane-local l ----
    float ps = 0.f;
#pragma unroll
    for (int cs = 0; cs < 4; ++cs)
#pragma unroll
      for (int r = 0; r < 4; ++r) {
        float p = __expf(st[cs][r] * 0.125f);
        if (last) {
          int cl = cs * 16 + quad * 4 + r;
          p = (cl > rel) ? 0.f : p;
        }
        st[cs][r] = p;
        ps += p;
      }
    l_i += ps;

    // ---- P[q][c] -> LDS (packed b64), cross-lane transpose to B-operand ----
#pragma unroll
    for (int cs = 0; cs < 4; ++cs) {
      bf16x4 pk;
#pragma unroll
      for (int r = 0; r < 4; ++r) pk[r] = (bf16)st[cs][r];
      *(bf16x4*)&Pw[l15 * PST + cs * 16 + quad * 4] = pk;
    }
    __asm__ __volatile__("" ::: "memory");   // W->R fence (cross-lane via LDS)
    bf16x8 bp0 = *(const bf16x8*)&Pw[l15 * PST + quad * 8];
    bf16x8 bp1 = *(const bf16x8*)&Pw[l15 * PST + 32 + quad * 8];
    __asm__ __volatile__("" ::: "memory");   // R->next-W fence

    // ---- O^T += V^T · P^T ----
#pragma unroll
    for (int nt = 0; nt < 4; ++nt) {
      o[nt] = __builtin_amdgcn_mfma_f32_16x16x32_bf16(av0[nt], bp0, o[nt], 0, 0, 0);
      o[nt] = __builtin_amdgcn_mfma_f32_16x16x32_bf16(av1[nt], bp1, o[nt], 0, 0, 0);
    }
  };

  int t = 0;
  for (;;) {
    body(ka0, ka1, kb0, kb1, t);
    if (t == nchunks - 1) break;
    ++t;
    body(kb0, kb1, ka0, ka1, t);
    if (t == nchunks - 1) break;
    ++t;
  }

  // ---- final l reduction across quads, normalize, store ----
  l_i += __shfl_xor(l_i, 16);
  l_i += __shfl_xor(l_i, 32);
  float inv = 1.0f / l_i;
#pragma unroll
  for (int nt = 0; nt < 4; ++nt) {
    bf16x4 ov;
#pragma unroll
    for (int r = 0; r < 4; ++r) ov[r] = (bf16)(o[nt][r] * inv);
    *(bf16x4*)&AO[(grow + l15) * D_MODEL + h * DH + nt * 16 + quad * 4] = ov;
  }
}

// ---------------------------------------------------------------------------
// 5. Output GEMM, m97 structure (unchanged)
// ---------------------------------------------------------------------------
__global__ __launch_bounds__(256) void out_gemm(
    const bf16* __restrict__ AO, const bf16* __restrict__ Wob,
    float* __restrict__ out) {
  __shared__ bf16 As[128 * 32];
  __shared__ bf16 Bs[128 * 32];

  int tid = threadIdx.x;
  int wave = tid >> 6, lane = tid & 63;
  int wm = wave >> 1, wn = wave & 1;
  int l15 = lane & 15, quad = lane >> 4;

  int row0 = blockIdx.x * 128;
  int nb = blockIdx.y * 128;

  int srow = tid >> 2;
  int schunk = tid & 3;
  const bf16* Ag = AO + (size_t)(row0 + srow) * D_MODEL + schunk * 8;
  const bf16* Bg = Wob + (size_t)(nb + srow) * D_MODEL + schunk * 8;
  bf16* Al0 = &As[srow * 32 + schunk * 8];
  bf16* Al1 = &As[(srow + 64) * 32 + schunk * 8];
  bf16* Bl0 = &Bs[srow * 32 + schunk * 8];
  bf16* Bl1 = &Bs[(srow + 64) * 32 + schunk * 8];

  f32x4 acc[4][4];
#pragma unroll
  for (int i = 0; i < 4; ++i)
#pragma unroll
    for (int j = 0; j < 4; ++j) acc[i][j] = (f32x4){0.f, 0.f, 0.f, 0.f};

  for (int k0 = 0; k0 < D_MODEL; k0 += 32) {
    async_copy16(Ag + k0, Al0);
    async_copy16(Ag + k0 + (size_t)64 * D_MODEL, Al1);
    async_copy16(Bg + k0, Bl0);
    async_copy16(Bg + k0 + (size_t)64 * D_MODEL, Bl1);
    __syncthreads();

    bf16x8 af[4], bfr[4];
#pragma unroll
    for (int i = 0; i < 4; ++i)
      af[i] = *(const bf16x8*)&As[(wm * 64 + i * 16 + l15) * 32 + quad * 8];
#pragma unroll
    for (int j = 0; j < 4; ++j)
      bfr[j] = *(const bf16x8*)&Bs[(wn * 64 + j * 16 + l15) * 32 + quad * 8];
#pragma unroll
    for (int i = 0; i < 4; ++i)
#pragma unroll
      for (int j = 0; j < 4; ++j)
        acc[i][j] = __builtin_amdgcn_mfma_f32_16x16x32_bf16(af[i], bfr[j],
                                                            acc[i][j], 0, 0, 0);
    __syncthreads();
  }

#pragma unroll
  for (int i = 0; i < 4; ++i) {
    int row = row0 + wm * 64 + i * 16 + quad * 4;
#pragma unroll
    for (int j = 0; j < 4; ++j) {
      int col = nb + wn * 64 + j * 16 + l15;
#pragma unroll
      for (int r = 0; r < 4; ++r)
        out[(size_t)(row + r) * D_MODEL + col] = acc[i][j][r];
    }
  }
}

// ---------------------------------------------------------------------------
extern "C" void kernel_launch(void* const* d_in, const int* in_sizes, int n_in,
                              void* d_out, int out_size, void* d_ws, size_t ws_size,
                              hipStream_t stream) {
  const float* X  = (const float*)d_in[0];
  const float* Wq = (const float*)d_in[1];
  const float* Wk = (const float*)d_in[2];
  const float* Wv = (const float*)d_in[3];
  const float* Wo = (const float*)d_in[4];
  const int*  pos = (const int*)d_in[5];
  float* out = (float*)d_out;

  char* w = (char*)d_ws;
  bf16* Xb  = (bf16*)w;  w += (size_t)M_ROWS * D_MODEL * 2;
  bf16* Wqb = (bf16*)w;  w += (size_t)D_MODEL * D_MODEL * 2;
  bf16* Wkb = (bf16*)w;  w += (size_t)D_MODEL * D_MODEL * 2;
  bf16* Wvb = (bf16*)w;  w += (size_t)D_MODEL * D_MODEL * 2;
  bf16* Wob = (bf16*)w;  w += (size_t)D_MODEL * D_MODEL * 2;
  bf16* Qb  = (bf16*)w;  w += (size_t)M_ROWS * D_MODEL * 2;
  bf16* Kb  = (bf16*)w;  w += (size_t)M_ROWS * D_MODEL * 2;
  bf16* Vb  = (bf16*)w;  w += (size_t)M_ROWS * D_MODEL * 2;
  bf16* AO  = (bf16*)w;  w += (size_t)M_ROWS * D_MODEL * 2;
  bf16* VT  = (bf16*)w;  w += (size_t)M_ROWS * D_MODEL * 2;

  cast_all<<<(NX + 4 * NW) / 256, 256, 0, stream>>>(X, Wq, Wk, Wv, Wo,
                                                    Xb, Wqb, Wkb, Wvb, Wob);
  qkv_gemm<<<dim3(M_ROWS / 128, 3 * D_MODEL / 128), 256, 0, stream>>>(
      Xb, Wqb, Wkb, Wvb, Qb, Kb, Vb);
  rope_kernel<<<(M_ROWS * NUM_HEADS * 32) / 256, 256, 0, stream>>>(Qb, Kb, pos);
  v_transpose<<<dim3(B_SZ * NUM_HEADS, T_SZ / 64), 256, 0, stream>>>(Vb, VT);
  attn_kernel<<<dim3(B_SZ * NUM_HEADS, T_SZ / 16), 64, 0, stream>>>(Qb, Kb, VT, AO);
  out_gemm<<<dim3(M_ROWS / 128, D_MODEL / 128), 256, 0, stream>>>(AO, Wob, out);
}